// Round 1
// baseline (5223.903 us; speedup 1.0000x reference)
//
#include <hip/hip_runtime.h>
#include <math.h>

#define Q 64          // number of queries
#define KD 768        // feature dim
#define BN 128        // bank rows per workgroup
#define BK 32         // k-chunk
#define TOPK 5
#define NTHREADS 256

// ---------------------------------------------------------------------------
// Kernel 1: normalize queries, store transposed qnT[k][q]  (so the GEMM can
// fetch 16 consecutive query values for one k with a single scalar load)
// ---------------------------------------------------------------------------
__global__ void qnorm_kernel(const float* __restrict__ q, float* __restrict__ qnT) {
    int r = blockIdx.x;            // query row
    int tid = threadIdx.x;
    __shared__ float red[4];
    float s = 0.f;
    for (int i = tid; i < KD; i += NTHREADS) { float v = q[r * KD + i]; s += v * v; }
    for (int off = 32; off > 0; off >>= 1) s += __shfl_down(s, off, 64);
    if ((tid & 63) == 0) red[tid >> 6] = s;
    __syncthreads();
    if (tid == 0) red[0] = 1.f / fmaxf(sqrtf(red[0] + red[1] + red[2] + red[3]), 1e-12f);
    __syncthreads();
    float inv = red[0];
    for (int i = tid; i < KD; i += NTHREADS) qnT[i * Q + r] = q[r * KD + i] * inv;
}

// ---------------------------------------------------------------------------
// Kernel 2: sim = qn . b / |b| for a BN-slab of bank rows; per-query top-5
// within the slab written to candidate arrays.
//   Wave w computes rows [16w, 16w+16) x all BN cols; lane holds cols
//   {2*lane, 2*lane+1}. A comes from scalar loads (wave-uniform), B from LDS.
// ---------------------------------------------------------------------------
__global__ __launch_bounds__(NTHREADS, 4) void sim_topk_kernel(
    const float* __restrict__ qnT, const float* __restrict__ bank,
    long long N, int nwg,
    float* __restrict__ cand_val, float* __restrict__ cand_id)
{
    __shared__ union {
        float Bs[BK][BN + 4];     // staged B chunk, transposed, padded
        float Cs[Q][BN + 4];      // C tile for the top-k phase
    } u;
    __shared__ float nred[2][BN];
    __shared__ float rnrm[BN];

    const int t = threadIdx.x;
    const int wg = blockIdx.x;
    const long long n0 = (long long)wg * BN;

    const int lane = t & 63;
    const int w = __builtin_amdgcn_readfirstlane(t >> 6);  // wave id 0..3 (uniform)
    const int r0 = w * 16;                                  // this wave's query rows

    // staging assignment: fixed bank-row per thread so |b|^2 accumulates locally
    const int sn = t & (BN - 1);      // 0..127
    const int h = t >> 7;             // 0 or 1
    const long long grow = n0 + sn;
    const bool valid = grow < N;
    const float* __restrict__ brow = bank + grow * (long long)KD;

    float acc[16][2];
#pragma unroll
    for (int r = 0; r < 16; ++r) { acc[r][0] = 0.f; acc[r][1] = 0.f; }
    float nsq = 0.f;

    float4 bv[4];
    // prefetch chunk 0
#pragma unroll
    for (int i = 0; i < 4; ++i) {
        int kq = h + 2 * i;
        bv[i] = valid ? *(const float4*)(brow + 0 + kq * 4) : make_float4(0.f, 0.f, 0.f, 0.f);
    }

    for (int k0 = 0; k0 < KD; k0 += BK) {
        __syncthreads();   // previous compute done reading Bs
#pragma unroll
        for (int i = 0; i < 4; ++i) {
            int kq = h + 2 * i;
            nsq += bv[i].x * bv[i].x + bv[i].y * bv[i].y + bv[i].z * bv[i].z + bv[i].w * bv[i].w;
            u.Bs[kq * 4 + 0][sn] = bv[i].x;
            u.Bs[kq * 4 + 1][sn] = bv[i].y;
            u.Bs[kq * 4 + 2][sn] = bv[i].z;
            u.Bs[kq * 4 + 3][sn] = bv[i].w;
        }
        __syncthreads();
        // prefetch next chunk while computing this one
        if (k0 + BK < KD) {
#pragma unroll
            for (int i = 0; i < 4; ++i) {
                int kq = h + 2 * i;
                bv[i] = valid ? *(const float4*)(brow + (k0 + BK) + kq * 4)
                              : make_float4(0.f, 0.f, 0.f, 0.f);
            }
        }
#pragma unroll
        for (int k = 0; k < BK; ++k) {
            float2 b = *(const float2*)&u.Bs[k][2 * lane];
            const float* arow = qnT + (k0 + k) * Q + r0;   // wave-uniform -> s_load
#pragma unroll
            for (int r = 0; r < 16; ++r) {
                float a = arow[r];
                acc[r][0] = fmaf(a, b.x, acc[r][0]);
                acc[r][1] = fmaf(a, b.y, acc[r][1]);
            }
        }
    }
    __syncthreads();           // done reading Bs; safe to overwrite with Cs

    nred[h][sn] = nsq;
#pragma unroll
    for (int r = 0; r < 16; ++r) {
        u.Cs[r0 + r][2 * lane] = acc[r][0];
        u.Cs[r0 + r][2 * lane + 1] = acc[r][1];
    }
    __syncthreads();
    if (t < BN) rnrm[t] = 1.f / fmaxf(sqrtf(nred[0][t] + nred[1][t]), 1e-12f);
    __syncthreads();

    if (t < Q) {
        float v[TOPK], id[TOPK];
#pragma unroll
        for (int j = 0; j < TOPK; ++j) { v[j] = -INFINITY; id[j] = 0.f; }
        long long rem = N - n0;
        int nvalid = rem < (long long)BN ? (int)rem : BN;
        for (int n = 0; n < nvalid; ++n) {
            float val = u.Cs[t][n] * rnrm[n];
            float cid = (float)(n0 + n);
#pragma unroll
            for (int j = 0; j < TOPK; ++j) {
                if (val > v[j]) {   // strict > : earlier (lower) index wins ties
                    float tv = v[j], ti = id[j];
                    v[j] = val; id[j] = cid;
                    val = tv; cid = ti;
                }
            }
        }
        long long base = (long long)t * ((long long)nwg * TOPK) + (long long)wg * TOPK;
#pragma unroll
        for (int j = 0; j < TOPK; ++j) {
            cand_val[base + j] = v[j];
            cand_id[base + j] = id[j];
        }
    }
}

// ---------------------------------------------------------------------------
// Kernel 3: merge per-WG candidates -> final top-5 per query.
// ---------------------------------------------------------------------------
__global__ void merge_kernel(const float* __restrict__ cand_val,
                             const float* __restrict__ cand_id,
                             int cpq, float* __restrict__ out)
{
    int q = blockIdx.x;
    int t = threadIdx.x;
    __shared__ float sv[NTHREADS * TOPK];
    __shared__ float si[NTHREADS * TOPK];

    float v[TOPK], id[TOPK];
#pragma unroll
    for (int j = 0; j < TOPK; ++j) { v[j] = -INFINITY; id[j] = 3.0e9f; }

    const float* cv = cand_val + (long long)q * cpq;
    const float* ci = cand_id + (long long)q * cpq;
    for (int n = t; n < cpq; n += NTHREADS) {
        float val = cv[n];
        float cid = ci[n];
#pragma unroll
        for (int j = 0; j < TOPK; ++j) {
            if (val > v[j] || (val == v[j] && cid < id[j])) {
                float tv = v[j], ti = id[j];
                v[j] = val; id[j] = cid;
                val = tv; cid = ti;
            }
        }
    }
#pragma unroll
    for (int j = 0; j < TOPK; ++j) { sv[t * TOPK + j] = v[j]; si[t * TOPK + j] = id[j]; }
    __syncthreads();

    if (t == 0) {
        float fv[TOPK], fi[TOPK];
#pragma unroll
        for (int j = 0; j < TOPK; ++j) { fv[j] = -INFINITY; fi[j] = 3.0e9f; }
        for (int n = 0; n < NTHREADS * TOPK; ++n) {
            float val = sv[n];
            float cid = si[n];
#pragma unroll
            for (int j = 0; j < TOPK; ++j) {
                if (val > fv[j] || (val == fv[j] && cid < fi[j])) {
                    float tv = fv[j], ti = fi[j];
                    fv[j] = val; fi[j] = cid;
                    val = tv; cid = ti;
                }
            }
        }
#pragma unroll
        for (int j = 0; j < TOPK; ++j) {
            out[q * TOPK + j] = fv[j];                 // values (fp32)
            out[Q * TOPK + q * TOPK + j] = fi[j];      // indices, stored as fp32
        }
    }
}

// ---------------------------------------------------------------------------
extern "C" void kernel_launch(void* const* d_in, const int* in_sizes, int n_in,
                              void* d_out, int out_size, void* d_ws, size_t ws_size,
                              hipStream_t stream) {
    const float* query = (const float*)d_in[0];
    const float* bank  = (const float*)d_in[1];
    long long N = (long long)in_sizes[1] / KD;     // 500000
    int nwg = (int)((N + BN - 1) / BN);            // 3907
    int cpq = nwg * TOPK;                          // candidates per query

    float* ws = (float*)d_ws;
    float* qnT      = ws;                          // KD*Q floats
    float* cand_val = qnT + (size_t)KD * Q;        // Q*cpq floats
    float* cand_id  = cand_val + (size_t)Q * cpq;  // Q*cpq floats

    float* out = (float*)d_out;

    qnorm_kernel<<<dim3(Q), dim3(NTHREADS), 0, stream>>>(query, qnT);
    sim_topk_kernel<<<dim3(nwg), dim3(NTHREADS), 0, stream>>>(
        qnT, bank, N, nwg, cand_val, cand_id);
    merge_kernel<<<dim3(Q), dim3(NTHREADS), 0, stream>>>(cand_val, cand_id, cpq, out);
}